// Round 7
// baseline (48.650 us; speedup 1.0000x reference)
//
#include <hip/hip_runtime.h>

// RBF interpolation weights:
//   sparse_coords: [B=4, N=256, 3] f32
//   grid_coords:   [M=65536, 3] f32
//   out:           [B, M, N] f32, normalized exp(-d2/(2*sigma^2))
//
// Write-bound: 268 MB out; device fill rate ~7.0 TB/s. Best: R5 = 46.4 µs.
// R7: persistent grid-stride form. 2048 blocks (8/CU); each wave runs the
// R5 inner loop (MPW=8, proven best) over 4 m-chunks, amortizing the sparse
// prologue 4x and cutting wave count 32K -> 8K. Tests wave-churn vs fixed
// overhead for the remaining ~8 µs over the write floor.

typedef float fx4 __attribute__((ext_vector_type(4)));

constexpr int B_ = 4;
constexpr int N_ = 256;
constexpr int M_ = 65536;
constexpr int MPW = 8;        // m-values per inner chunk per wave
constexpr int BLOCKS_X = 512; // 512 x 4(b) = 2048 blocks = 8 per CU
constexpr int CHUNK = 4 * MPW;            // m per block per iteration (4 waves)
constexpr int ITERS = M_ / (BLOCKS_X * CHUNK);  // 65536 / 16384 = 4
// -1/(2*sigma^2) * log2(e) = -50 * 1.4426950408889634
constexpr float NEG50_LOG2E = -72.13475204444817f;

__global__ __launch_bounds__(256) void rbf_weights_kernel(
    const float* __restrict__ sparse,  // [B, N, 3]
    const float* __restrict__ grid,    // [M, 3]
    float* __restrict__ out)           // [B, M, N]
{
    const int tid  = threadIdx.x;
    const int lane = tid & 63;
    const int wave = tid >> 6;
    const int b    = blockIdx.y;

    // Per-lane sparse points: n = 4*lane + k (contiguous -> float4 store).
    // Loaded ONCE per wave, reused for all ITERS * MPW m-values.
    const float* sp = sparse + (size_t)b * N_ * 3 + (size_t)lane * 12;
    const fx4 p0 = *(const fx4*)(sp + 0);
    const fx4 p1 = *(const fx4*)(sp + 4);
    const fx4 p2 = *(const fx4*)(sp + 8);

    const float sx[4] = {p0.x, p0.w, p1.z, p2.y};
    const float sy[4] = {p0.y, p1.x, p1.w, p2.z};
    const float sz[4] = {p0.z, p1.y, p2.x, p2.w};
    float s2[4];
#pragma unroll
    for (int j = 0; j < 4; ++j)
        s2[j] = sx[j] * sx[j] + sy[j] * sy[j] + sz[j] * sz[j];

    for (int it = 0; it < ITERS; ++it) {
        const int m0 = ((it * BLOCKS_X + blockIdx.x) * 4 + wave) * MPW;

        // Prefetch this chunk's MPW grid points (wave-uniform broadcast loads).
        float gx[MPW], gy[MPW], gz[MPW];
        const float* g = grid + (size_t)m0 * 3;
#pragma unroll
        for (int mi = 0; mi < MPW; ++mi) {
            gx[mi] = g[mi * 3 + 0];
            gy[mi] = g[mi * 3 + 1];
            gz[mi] = g[mi * 3 + 2];
        }

        float* outb = out + ((size_t)b * M_ + m0) * N_ + (size_t)lane * 4;

#pragma unroll
        for (int mi = 0; mi < MPW; ++mi) {
            const float g2  = gx[mi] * gx[mi] + gy[mi] * gy[mi] + gz[mi] * gz[mi];
            const float ghx = -2.0f * gx[mi];
            const float ghy = -2.0f * gy[mi];
            const float ghz = -2.0f * gz[mi];

            float w[4];
            float lsum = 0.0f;
#pragma unroll
            for (int j = 0; j < 4; ++j) {
                float d2 = fmaf(ghx, sx[j], fmaf(ghy, sy[j], fmaf(ghz, sz[j], g2 + s2[j])));
                const float t = fminf(d2 * NEG50_LOG2E, 0.0f);
                const float e = exp2f(t);
                w[j] = e;
                lsum += e;
            }

#pragma unroll
            for (int off = 32; off; off >>= 1) lsum += __shfl_xor(lsum, off);

            const float inv = 1.0f / (lsum + 1e-8f);

            fx4 o4;
            o4.x = w[0] * inv;
            o4.y = w[1] * inv;
            o4.z = w[2] * inv;
            o4.w = w[3] * inv;
            *(fx4*)(outb + (size_t)mi * N_) = o4;
        }
    }
}

extern "C" void kernel_launch(void* const* d_in, const int* in_sizes, int n_in,
                              void* d_out, int out_size, void* d_ws, size_t ws_size,
                              hipStream_t stream) {
    const float* sparse = (const float*)d_in[0];  // [4, 256, 3]
    const float* grid   = (const float*)d_in[1];  // [65536, 3]
    float* out = (float*)d_out;                   // [4, 65536, 256]

    dim3 grid_dim(BLOCKS_X, B_, 1);  // 512 x 4 = 2048 blocks
    dim3 block_dim(256, 1, 1);
    rbf_weights_kernel<<<grid_dim, block_dim, 0, stream>>>(sparse, grid, out);
}

// Round 8
// 48.062 us; speedup vs baseline: 1.0122x; 1.0122x over previous
//
#include <hip/hip_runtime.h>

// RBF interpolation weights:
//   sparse_coords: [B=4, N=256, 3] f32
//   grid_coords:   [M=65536, 3] f32
//   out:           [B, M, N] f32, normalized exp(-d2/(2*sigma^2))
//
// Write-bound: 268 MB out; device fill rate ~7.0 TB/s. Best: R5 = 46.4 µs
// (MPW=8). Probe history: fewer waves (R4 MPW=16, R7 persistent) both hurt;
// more waves never tested. R8: MPW=4 -> 64K waves (2x R5), same structure
// otherwise. Tests whether store-latency hiding via wave parallelism is the
// residual constraint.

typedef float fx4 __attribute__((ext_vector_type(4)));

constexpr int B_ = 4;
constexpr int N_ = 256;
constexpr int M_ = 65536;
constexpr int MPW = 4;  // m-values per wave (R5 had 8)
// -1/(2*sigma^2) * log2(e) = -50 * 1.4426950408889634
constexpr float NEG50_LOG2E = -72.13475204444817f;

__global__ __launch_bounds__(256) void rbf_weights_kernel(
    const float* __restrict__ sparse,  // [B, N, 3]
    const float* __restrict__ grid,    // [M, 3]
    float* __restrict__ out)           // [B, M, N]
{
    const int tid  = threadIdx.x;
    const int lane = tid & 63;
    const int wave = tid >> 6;
    const int b    = blockIdx.y;
    const int m0   = (blockIdx.x * 4 + wave) * MPW;

    // Per-lane sparse points: n = 4*lane + k (contiguous -> float4 store).
    const float* sp = sparse + (size_t)b * N_ * 3 + (size_t)lane * 12;
    const fx4 p0 = *(const fx4*)(sp + 0);
    const fx4 p1 = *(const fx4*)(sp + 4);
    const fx4 p2 = *(const fx4*)(sp + 8);

    const float sx[4] = {p0.x, p0.w, p1.z, p2.y};
    const float sy[4] = {p0.y, p1.x, p1.w, p2.z};
    const float sz[4] = {p0.z, p1.y, p2.x, p2.w};
    float s2[4];
#pragma unroll
    for (int j = 0; j < 4; ++j)
        s2[j] = sx[j] * sx[j] + sy[j] * sy[j] + sz[j] * sz[j];

    // Prefetch this wave's MPW grid points (wave-uniform broadcast loads).
    float gx[MPW], gy[MPW], gz[MPW];
    const float* g = grid + (size_t)m0 * 3;
#pragma unroll
    for (int mi = 0; mi < MPW; ++mi) {
        gx[mi] = g[mi * 3 + 0];
        gy[mi] = g[mi * 3 + 1];
        gz[mi] = g[mi * 3 + 2];
    }

    float* outb = out + ((size_t)b * M_ + m0) * N_ + (size_t)lane * 4;

#pragma unroll
    for (int mi = 0; mi < MPW; ++mi) {
        const float g2  = gx[mi] * gx[mi] + gy[mi] * gy[mi] + gz[mi] * gz[mi];
        const float ghx = -2.0f * gx[mi];
        const float ghy = -2.0f * gy[mi];
        const float ghz = -2.0f * gz[mi];

        float w[4];
        float lsum = 0.0f;
#pragma unroll
        for (int j = 0; j < 4; ++j) {
            float d2 = fmaf(ghx, sx[j], fmaf(ghy, sy[j], fmaf(ghz, sz[j], g2 + s2[j])));
            const float t = fminf(d2 * NEG50_LOG2E, 0.0f);
            const float e = exp2f(t);
            w[j] = e;
            lsum += e;
        }

#pragma unroll
        for (int off = 32; off; off >>= 1) lsum += __shfl_xor(lsum, off);

        const float inv = 1.0f / (lsum + 1e-8f);

        fx4 o4;
        o4.x = w[0] * inv;
        o4.y = w[1] * inv;
        o4.z = w[2] * inv;
        o4.w = w[3] * inv;
        *(fx4*)(outb + (size_t)mi * N_) = o4;
    }
}

extern "C" void kernel_launch(void* const* d_in, const int* in_sizes, int n_in,
                              void* d_out, int out_size, void* d_ws, size_t ws_size,
                              hipStream_t stream) {
    const float* sparse = (const float*)d_in[0];  // [4, 256, 3]
    const float* grid   = (const float*)d_in[1];  // [65536, 3]
    float* out = (float*)d_out;                   // [4, 65536, 256]

    dim3 grid_dim(M_ / (4 * MPW), B_, 1);  // 4096 x 4
    dim3 block_dim(256, 1, 1);
    rbf_weights_kernel<<<grid_dim, block_dim, 0, stream>>>(sparse, grid, out);
}

// Round 9
// 46.542 us; speedup vs baseline: 1.0453x; 1.0327x over previous
//
#include <hip/hip_runtime.h>

// RBF interpolation weights:
//   sparse_coords: [B=4, N=256, 3] f32
//   grid_coords:   [M=65536, 3] f32
//   out:           [B, M, N] f32, normalized exp(-d2/(2*sigma^2))
//
// FINAL (R5 config, proven best = 46.4 µs, 5.78 TB/s effective on 268 MB of
// output; device fill-rate ceiling measured at ~6.9-7.0 TB/s on 1 GB).
// Probe history: float4 stores +1.3 µs; NT stores -11; MPW=16 -2..-11;
// MPW=4 -1.6; persistent grid-stride -2.2; phase-batched reduce -2.1.
// MPW=8 with plain float4 stores and per-wave register-resident sparse
// points is the measured optimum; residual over the 38.7 µs write floor is
// fixed launch/ramp overhead + the per-m serial exp->reduce->store chain.

typedef float fx4 __attribute__((ext_vector_type(4)));

constexpr int B_ = 4;
constexpr int N_ = 256;
constexpr int M_ = 65536;
constexpr int MPW = 8;  // m-values per wave (measured optimum)
// -1/(2*sigma^2) * log2(e) = -50 * 1.4426950408889634
constexpr float NEG50_LOG2E = -72.13475204444817f;

__global__ __launch_bounds__(256) void rbf_weights_kernel(
    const float* __restrict__ sparse,  // [B, N, 3]
    const float* __restrict__ grid,    // [M, 3]
    float* __restrict__ out)           // [B, M, N]
{
    const int tid  = threadIdx.x;
    const int lane = tid & 63;
    const int wave = tid >> 6;
    const int b    = blockIdx.y;
    const int m0   = (blockIdx.x * 4 + wave) * MPW;

    // Per-lane sparse points: n = 4*lane + k (contiguous -> float4 store).
    const float* sp = sparse + (size_t)b * N_ * 3 + (size_t)lane * 12;
    const fx4 p0 = *(const fx4*)(sp + 0);
    const fx4 p1 = *(const fx4*)(sp + 4);
    const fx4 p2 = *(const fx4*)(sp + 8);

    const float sx[4] = {p0.x, p0.w, p1.z, p2.y};
    const float sy[4] = {p0.y, p1.x, p1.w, p2.z};
    const float sz[4] = {p0.z, p1.y, p2.x, p2.w};
    float s2[4];
#pragma unroll
    for (int j = 0; j < 4; ++j)
        s2[j] = sx[j] * sx[j] + sy[j] * sy[j] + sz[j] * sz[j];

    // Prefetch this wave's MPW grid points (wave-uniform broadcast loads).
    float gx[MPW], gy[MPW], gz[MPW];
    const float* g = grid + (size_t)m0 * 3;
#pragma unroll
    for (int mi = 0; mi < MPW; ++mi) {
        gx[mi] = g[mi * 3 + 0];
        gy[mi] = g[mi * 3 + 1];
        gz[mi] = g[mi * 3 + 2];
    }

    float* outb = out + ((size_t)b * M_ + m0) * N_ + (size_t)lane * 4;

#pragma unroll
    for (int mi = 0; mi < MPW; ++mi) {
        const float g2  = gx[mi] * gx[mi] + gy[mi] * gy[mi] + gz[mi] * gz[mi];
        const float ghx = -2.0f * gx[mi];
        const float ghy = -2.0f * gy[mi];
        const float ghz = -2.0f * gz[mi];

        float w[4];
        float lsum = 0.0f;
#pragma unroll
        for (int j = 0; j < 4; ++j) {
            // d2 = g2 + s2 - 2*(g.s), as a pure FMA chain
            float d2 = fmaf(ghx, sx[j], fmaf(ghy, sy[j], fmaf(ghz, sz[j], g2 + s2[j])));
            // exp(-50*d2) = exp2(d2 * -50*log2e); clamp d2>=0 <=> t<=0
            const float t = fminf(d2 * NEG50_LOG2E, 0.0f);
            const float e = exp2f(t);
            w[j] = e;
            lsum += e;
        }

        // Wave-wide sum over all 64 lanes (full n-row).
#pragma unroll
        for (int off = 32; off; off >>= 1) lsum += __shfl_xor(lsum, off);

        const float inv = 1.0f / (lsum + 1e-8f);

        fx4 o4;
        o4.x = w[0] * inv;
        o4.y = w[1] * inv;
        o4.z = w[2] * inv;
        o4.w = w[3] * inv;
        *(fx4*)(outb + (size_t)mi * N_) = o4;
    }
}

extern "C" void kernel_launch(void* const* d_in, const int* in_sizes, int n_in,
                              void* d_out, int out_size, void* d_ws, size_t ws_size,
                              hipStream_t stream) {
    const float* sparse = (const float*)d_in[0];  // [4, 256, 3]
    const float* grid   = (const float*)d_in[1];  // [65536, 3]
    float* out = (float*)d_out;                   // [4, 65536, 256]

    dim3 grid_dim(M_ / (4 * MPW), B_, 1);  // 2048 x 4
    dim3 block_dim(256, 1, 1);
    rbf_weights_kernel<<<grid_dim, block_dim, 0, stream>>>(sparse, grid, out);
}